// Round 6
// baseline (239.911 us; speedup 1.0000x reference)
//
#include <hip/hip_runtime.h>
#include <math.h>

#define BATCH 2
#define SEQ 2048
#define DMODEL 512
#define NH 8
#define HDIM 64
#define MTOT (BATCH * SEQ)              // 4096
#define QSIZE (BATCH * NH * SEQ * HDIM) // 2097152 elems per tensor
#define WSIZE (DMODEL * DMODEL)         // 262144 elems per weight

typedef __attribute__((ext_vector_type(8))) short bf16x8;
typedef __attribute__((ext_vector_type(4))) float f32x4;

__device__ inline unsigned short f2bf(float f) {
    union { float f; unsigned u; } v; v.f = f;
    unsigned u = v.u;
    u += 0x7fffu + ((u >> 16) & 1u);
    return (unsigned short)(u >> 16);
}
__device__ inline unsigned pack2(float lo, float hi) {
    return (unsigned)f2bf(lo) | ((unsigned)f2bf(hi) << 16);
}

// LDS row stride: 72 elems = 144 B (16B-aligned; 36-dword rows rotate banks
// by 4 per row).
#define LSTR 72

// ws layout (bf16 elems):
#define WS_Q   ((size_t)0)
#define WS_K   ((size_t)QSIZE)
#define WS_V   (2 * (size_t)QSIZE)        // [B,H,HD,S] transposed
#define WS_CTX (3 * (size_t)QSIZE)
#define WS_WT  (4 * (size_t)QSIZE)        // 4 transposed weights
#define WS_ABF (4 * (size_t)QSIZE + 4 * (size_t)WSIZE)  // bf16 inputs q,k,v

// ---------------------------------------------------------------------------
// Kernel 0a: transpose + bf16-convert the 4 weight matrices.
// ---------------------------------------------------------------------------
__global__ __launch_bounds__(256) void wt_prep_kernel(
    const float* __restrict__ Wq, const float* __restrict__ Wk,
    const float* __restrict__ Wv, const float* __restrict__ Wo,
    unsigned short* __restrict__ wt)
{
    const int z = blockIdx.z;
    const float* W = (z == 0) ? Wq : (z == 1) ? Wk : (z == 2) ? Wv : Wo;
    unsigned short* Wt = wt + (size_t)z * WSIZE;

    __shared__ float T[32][33];
    const int tid = threadIdx.x;
    const int k0 = blockIdx.x * 32, n0 = blockIdx.y * 32;

    {
        int r = tid >> 3, c = (tid & 7) * 4;
        float4 v = *(const float4*)&W[(size_t)(k0 + r) * DMODEL + n0 + c];
        T[r][c + 0] = v.x; T[r][c + 1] = v.y; T[r][c + 2] = v.z; T[r][c + 3] = v.w;
    }
    __syncthreads();
    {
        int n = tid >> 3, c = (tid & 7) * 4;
        uint2 o;
        o.x = pack2(T[c + 0][n], T[c + 1][n]);
        o.y = pack2(T[c + 2][n], T[c + 3][n]);
        *(uint2*)&Wt[(size_t)(n0 + n) * DMODEL + k0 + c] = o;
    }
}

// ---------------------------------------------------------------------------
// Kernel 0b: convert fp32 inputs -> bf16 (row-major unchanged layout).
// ---------------------------------------------------------------------------
__global__ __launch_bounds__(256) void inp_prep_kernel(
    const float* __restrict__ qin, const float* __restrict__ kin,
    const float* __restrict__ vin, unsigned short* __restrict__ abf)
{
    const int z = blockIdx.y;
    const float* src = (z == 0) ? qin : (z == 1) ? kin : vin;
    unsigned short* dst = abf + (size_t)z * QSIZE;

    const size_t i = ((size_t)blockIdx.x * 256 + threadIdx.x) * 8;
    float4 f0 = *(const float4*)(src + i);
    float4 f1 = *(const float4*)(src + i + 4);
    uint4 o;
    o.x = pack2(f0.x, f0.y); o.y = pack2(f0.z, f0.w);
    o.z = pack2(f1.x, f1.y); o.w = pack2(f1.z, f1.w);
    *(uint4*)(dst + i) = o;
}

// ---------------------------------------------------------------------------
// Kernel 1: fused QKV projection, bf16 MFMA, 128x128 tiles, prefetched.
// Q/K: A-operand = Wt (C rows = head-dim) -> uint2 stores into [B,H,S,HD].
// V:   A-operand = tokens (C rows = token) -> uint2 stores into [B,H,HD,S].
// Q scaled by 0.125 (bias folded). grid (4, 32, 3).
// Staging: each thread covers 32 cols of one row (4x uint4) per matrix.
// ---------------------------------------------------------------------------
__global__ __launch_bounds__(256) void qkv_mfma_kernel(
    unsigned short* __restrict__ ws,
    const float* __restrict__ bq, const float* __restrict__ bk,
    const float* __restrict__ bv)
{
    const int which = blockIdx.z;
    const unsigned short* A  = ws + WS_ABF + (size_t)which * QSIZE;
    const unsigned short* Wt = ws + WS_WT + (size_t)which * WSIZE;
    const float* bias = (which == 0) ? bq : (which == 1) ? bk : bv;
    unsigned short* out = ws + (size_t)which * QSIZE;

    __shared__ __align__(16) short As[128][LSTR];  // tokens x k
    __shared__ __align__(16) short Bs[128][LSTR];  // dims x k

    const int tid = threadIdx.x;
    const int lane = tid & 63, wave = tid >> 6;
    const int lrow = lane & 15, quad = lane >> 4;
    const int m0 = blockIdx.y * 128, n0 = blockIdx.x * 128;

    const int sr = tid >> 1, sh = (tid & 1) * 32;   // row, 32-col half

    uint4 pa[4], pb[4];
    {
        const unsigned short* ap = A + (size_t)(m0 + sr) * DMODEL + sh;
        pa[0] = *(const uint4*)ap;        pa[1] = *(const uint4*)(ap + 8);
        pa[2] = *(const uint4*)(ap + 16); pa[3] = *(const uint4*)(ap + 24);
        const unsigned short* wp = Wt + (size_t)(n0 + sr) * DMODEL + sh;
        pb[0] = *(const uint4*)wp;        pb[1] = *(const uint4*)(wp + 8);
        pb[2] = *(const uint4*)(wp + 16); pb[3] = *(const uint4*)(wp + 24);
    }

    f32x4 acc[2][8];
    #pragma unroll
    for (int i = 0; i < 2; ++i)
        #pragma unroll
        for (int n = 0; n < 8; ++n) acc[i][n] = f32x4{0.f, 0.f, 0.f, 0.f};

    const bool tr = (which < 2);  // Q,K: A-operand = Wt (dims), B = tokens
    const short (*At)[LSTR] = tr ? Bs : As;
    const short (*Bt)[LSTR] = tr ? As : Bs;

    for (int k0 = 0; k0 < DMODEL; k0 += 64) {
        __syncthreads();
        *(uint4*)&As[sr][sh]      = pa[0];
        *(uint4*)&As[sr][sh + 8]  = pa[1];
        *(uint4*)&As[sr][sh + 16] = pa[2];
        *(uint4*)&As[sr][sh + 24] = pa[3];
        *(uint4*)&Bs[sr][sh]      = pb[0];
        *(uint4*)&Bs[sr][sh + 8]  = pb[1];
        *(uint4*)&Bs[sr][sh + 16] = pb[2];
        *(uint4*)&Bs[sr][sh + 24] = pb[3];
        __syncthreads();
        {   // prefetch next k-tile (clamped; redundant reload on last iter)
            const int k0n = (k0 + 64 < DMODEL) ? k0 + 64 : k0;
            const unsigned short* ap = A + (size_t)(m0 + sr) * DMODEL + k0n + sh;
            pa[0] = *(const uint4*)ap;        pa[1] = *(const uint4*)(ap + 8);
            pa[2] = *(const uint4*)(ap + 16); pa[3] = *(const uint4*)(ap + 24);
            const unsigned short* wp = Wt + (size_t)(n0 + sr) * DMODEL + k0n + sh;
            pb[0] = *(const uint4*)wp;        pb[1] = *(const uint4*)(wp + 8);
            pb[2] = *(const uint4*)(wp + 16); pb[3] = *(const uint4*)(wp + 24);
        }
        #pragma unroll
        for (int s = 0; s < 2; ++s) {
            bf16x8 af[2];
            #pragma unroll
            for (int i = 0; i < 2; ++i)
                af[i] = *(const bf16x8*)&At[wave * 32 + i * 16 + lrow][s * 32 + quad * 8];
            #pragma unroll
            for (int n = 0; n < 8; ++n) {
                bf16x8 bf = *(const bf16x8*)&Bt[n * 16 + lrow][s * 32 + quad * 8];
                acc[0][n] = __builtin_amdgcn_mfma_f32_16x16x32_bf16(af[0], bf, acc[0][n], 0, 0, 0);
                acc[1][n] = __builtin_amdgcn_mfma_f32_16x16x32_bf16(af[1], bf, acc[1][n], 0, 0, 0);
            }
        }
    }

    if (tr) {
        // Q/K: rows = dim, cols = token; store [B,H,S,HD] vectorized over hd.
        const float scale = (which == 0) ? 0.125f : 1.0f;
        #pragma unroll
        for (int i = 0; i < 2; ++i) {
            const int dimb = n0 + wave * 32 + i * 16 + quad * 4;
            const float4 b4 = *(const float4*)&bias[dimb];
            const int h_ = dimb >> 6, hd_ = dimb & 63;
            #pragma unroll
            for (int n = 0; n < 8; ++n) {
                const int tok = m0 + n * 16 + lrow;
                const int b_ = tok >> 11, s_ = tok & (SEQ - 1);
                uint2 o;
                o.x = pack2((acc[i][n][0] + b4.x) * scale, (acc[i][n][1] + b4.y) * scale);
                o.y = pack2((acc[i][n][2] + b4.z) * scale, (acc[i][n][3] + b4.w) * scale);
                *(uint2*)&out[((size_t)((b_ * NH + h_) * SEQ + s_)) * HDIM + hd_] = o;
            }
        }
    } else {
        // V: rows = token, cols = dim; store [B,H,HD,S] vectorized over s.
        #pragma unroll
        for (int n = 0; n < 8; ++n) {
            const int col = n0 + n * 16 + lrow;
            const int h_ = col >> 6, hd_ = col & 63;
            const float bv_ = bias[col];
            #pragma unroll
            for (int i = 0; i < 2; ++i) {
                const int tok = m0 + wave * 32 + i * 16 + quad * 4;
                const int b_ = tok >> 11, s_ = tok & (SEQ - 1);
                uint2 o;
                o.x = pack2(acc[i][n][0] + bv_, acc[i][n][1] + bv_);
                o.y = pack2(acc[i][n][2] + bv_, acc[i][n][3] + bv_);
                *(uint2*)&out[((size_t)((b_ * NH + h_) * HDIM + hd_)) * SEQ + s_] = o;
            }
        }
    }
}

// ---------------------------------------------------------------------------
// Kernel 2: bf16 MFMA flash attention, S^T formulation, Q-tile 128.
// grid = (B*H = 16, S/128 = 16), 256 thr; wave owns 32 q rows (2 j-subtiles).
// Register-prefetched K/V staging; each LDS fragment read feeds 2 MFMAs.
// ---------------------------------------------------------------------------
__global__ __launch_bounds__(256) void attn_mfma_kernel(
    const unsigned short* __restrict__ ws, unsigned short* __restrict__ ctx)
{
    const unsigned short* Q = ws + WS_Q;   // pre-scaled by 0.125
    const unsigned short* K = ws + WS_K;
    const unsigned short* V = ws + WS_V;   // [B,H,HD,S]

    __shared__ __align__(16) short Ks[64][LSTR];   // K[key][hd]
    __shared__ __align__(16) short Vt[64][LSTR];   // V^T[hd][key]
    __shared__ __align__(16) short Ps[128][LSTR];  // P[q][key] (per-wave rows)

    const int bh = blockIdx.x;
    const int q0 = blockIdx.y * 128;
    const int tid = threadIdx.x;
    const int lane = tid & 63, wave = tid >> 6;
    const int lrow = lane & 15, quad = lane >> 4;
    const size_t base = (size_t)bh * SEQ * HDIM;

    // Q B-frags: lane supplies Q[q=wave*32+j*16+lrow][d=half*32+quad*8+..]
    bf16x8 qb[2][2];
    #pragma unroll
    for (int j = 0; j < 2; ++j) {
        const unsigned short* qr = Q + base + (size_t)(q0 + wave * 32 + j * 16 + lrow) * HDIM;
        qb[j][0] = *(const bf16x8*)(qr + quad * 8);
        qb[j][1] = *(const bf16x8*)(qr + 32 + quad * 8);
    }

    float m_prev[2] = {-1e30f, -1e30f}, l_run[2] = {0.f, 0.f};
    f32x4 oacc[4][2];   // O^T: [d-tile md][j]; row d = md*16+quad*4+r, col q
    #pragma unroll
    for (int md = 0; md < 4; ++md)
        #pragma unroll
        for (int j = 0; j < 2; ++j) oacc[md][j] = f32x4{0.f, 0.f, 0.f, 0.f};

    const int kr = tid >> 2, kc = (tid & 3) * 16;  // K staging: key row, 16 hd
    const int vr = tid >> 2, vq = (tid & 3) * 16;  // Vt staging: hd row, 16 keys

    uint4 kpre[2], vpre[2];
    {
        const unsigned short* kp = K + base + (size_t)kr * HDIM + kc;
        kpre[0] = *(const uint4*)kp;  kpre[1] = *(const uint4*)(kp + 8);
        const unsigned short* vp = V + base + (size_t)vr * SEQ + vq;
        vpre[0] = *(const uint4*)vp;  vpre[1] = *(const uint4*)(vp + 8);
    }

    for (int kt = 0; kt < SEQ; kt += 64) {
        __syncthreads();   // prior iter's reads of Ks/Vt complete
        *(uint4*)&Ks[kr][kc]     = kpre[0];
        *(uint4*)&Ks[kr][kc + 8] = kpre[1];
        *(uint4*)&Vt[vr][vq]     = vpre[0];
        *(uint4*)&Vt[vr][vq + 8] = vpre[1];
        __syncthreads();
        {   // prefetch next tile (clamped; redundant last iter)
            const int ktn = (kt + 64 < SEQ) ? kt + 64 : kt;
            const unsigned short* kp = K + base + (size_t)(ktn + kr) * HDIM + kc;
            kpre[0] = *(const uint4*)kp;  kpre[1] = *(const uint4*)(kp + 8);
            const unsigned short* vp = V + base + (size_t)vr * SEQ + ktn + vq;
            vpre[0] = *(const uint4*)vp;  vpre[1] = *(const uint4*)(vp + 8);
        }

        // ---- S^T = K·Q^T : st[m][j], keys m*16+quad*4+r, q = j*16+lrow ----
        f32x4 st[4][2];
        #pragma unroll
        for (int m = 0; m < 4; ++m) {
            bf16x8 ka0 = *(const bf16x8*)&Ks[m * 16 + lrow][quad * 8];
            bf16x8 ka1 = *(const bf16x8*)&Ks[m * 16 + lrow][32 + quad * 8];
            #pragma unroll
            for (int j = 0; j < 2; ++j) {
                f32x4 z = f32x4{0.f, 0.f, 0.f, 0.f};
                z = __builtin_amdgcn_mfma_f32_16x16x32_bf16(ka0, qb[j][0], z, 0, 0, 0);
                z = __builtin_amdgcn_mfma_f32_16x16x32_bf16(ka1, qb[j][1], z, 0, 0, 0);
                st[m][j] = z;
            }
        }

        // ---- online softmax per j (q = wave*32+j*16+lrow) ----
        #pragma unroll
        for (int j = 0; j < 2; ++j) {
            float tmax = st[0][j][0];
            #pragma unroll
            for (int m = 0; m < 4; ++m)
                #pragma unroll
                for (int r = 0; r < 4; ++r) tmax = fmaxf(tmax, st[m][j][r]);
            tmax = fmaxf(tmax, __shfl_xor(tmax, 16));
            tmax = fmaxf(tmax, __shfl_xor(tmax, 32));

            const float mnew = fmaxf(m_prev[j], tmax);
            const float alpha = __expf(m_prev[j] - mnew);
            float p[4][4];
            float tsum = 0.f;
            #pragma unroll
            for (int m = 0; m < 4; ++m)
                #pragma unroll
                for (int r = 0; r < 4; ++r) {
                    p[m][r] = __expf(st[m][j][r] - mnew);
                    tsum += p[m][r];
                }
            tsum += __shfl_xor(tsum, 16);
            tsum += __shfl_xor(tsum, 32);
            l_run[j] = l_run[j] * alpha + tsum;
            m_prev[j] = mnew;
            #pragma unroll
            for (int md = 0; md < 4; ++md) {
                oacc[md][j][0] *= alpha; oacc[md][j][1] *= alpha;
                oacc[md][j][2] *= alpha; oacc[md][j][3] *= alpha;
            }
            const int prow = wave * 32 + j * 16 + lrow;
            #pragma unroll
            for (int m = 0; m < 4; ++m) {
                uint2 o;
                o.x = pack2(p[m][0], p[m][1]);
                o.y = pack2(p[m][2], p[m][3]);
                *(uint2*)&Ps[prow][m * 16 + quad * 4] = o;
            }
        }
        // Ps rows are wave-private: compiler orders write->read via lgkmcnt.

        // ---- O^T += V^T·P^T ----
        bf16x8 pb[2][2];
        #pragma unroll
        for (int j = 0; j < 2; ++j) {
            pb[j][0] = *(const bf16x8*)&Ps[wave * 32 + j * 16 + lrow][quad * 8];
            pb[j][1] = *(const bf16x8*)&Ps[wave * 32 + j * 16 + lrow][32 + quad * 8];
        }
        #pragma unroll
        for (int md = 0; md < 4; ++md) {
            bf16x8 va0 = *(const bf16x8*)&Vt[md * 16 + lrow][quad * 8];
            bf16x8 va1 = *(const bf16x8*)&Vt[md * 16 + lrow][32 + quad * 8];
            #pragma unroll
            for (int j = 0; j < 2; ++j) {
                oacc[md][j] = __builtin_amdgcn_mfma_f32_16x16x32_bf16(va0, pb[j][0], oacc[md][j], 0, 0, 0);
                oacc[md][j] = __builtin_amdgcn_mfma_f32_16x16x32_bf16(va1, pb[j][1], oacc[md][j], 0, 0, 0);
            }
        }
    }

    // ---- epilogue: normalize, vectorized bf16 ctx [B,S,D] ----
    const int b_ = bh >> 3, h_ = bh & 7;
    #pragma unroll
    for (int j = 0; j < 2; ++j) {
        const float inv = 1.f / l_run[j];
        const int qg = q0 + wave * 32 + j * 16 + lrow;
        unsigned short* crow = ctx + ((size_t)(b_ * SEQ + qg)) * DMODEL + h_ * HDIM;
        #pragma unroll
        for (int md = 0; md < 4; ++md) {
            uint2 o;
            o.x = pack2(oacc[md][j][0] * inv, oacc[md][j][1] * inv);
            o.y = pack2(oacc[md][j][2] * inv, oacc[md][j][3] * inv);
            *(uint2*)&crow[md * 16 + quad * 4] = o;
        }
    }
}

// ---------------------------------------------------------------------------
// Kernel 3: output projection, bf16 MFMA, 64x128 tiles (tokens x dims),
// A=Wt orientation -> float4 epilogue stores. grid (4, 64), prefetched.
// ---------------------------------------------------------------------------
__global__ __launch_bounds__(256) void out_proj_mfma_kernel(
    const unsigned short* __restrict__ ws, const float* __restrict__ bo,
    float* __restrict__ out)
{
    const unsigned short* ctx = ws + WS_CTX;
    const unsigned short* Wt  = ws + WS_WT + 3 * (size_t)WSIZE;

    __shared__ __align__(16) short As[64][LSTR];   // tokens x k
    __shared__ __align__(16) short Bs[128][LSTR];  // dims x k

    const int tid = threadIdx.x;
    const int lane = tid & 63, wave = tid >> 6;
    const int lrow = lane & 15, quad = lane >> 4;
    const int m0 = blockIdx.y * 64, n0 = blockIdx.x * 128;

    const int ar = tid >> 2, ac = (tid & 3) * 16;   // As: row, 16-col quarter
    const int br = tid >> 1, bc = (tid & 1) * 32;   // Bs: row, 32-col half

    uint4 pa0, pa1, pb[4];
    {
        const unsigned short* ap = ctx + (size_t)(m0 + ar) * DMODEL + ac;
        pa0 = *(const uint4*)ap;
        pa1 = *(const uint4*)(ap + 8);
        const unsigned short* wp = Wt + (size_t)(n0 + br) * DMODEL + bc;
        pb[0] = *(const uint4*)wp;        pb[1] = *(const uint4*)(wp + 8);
        pb[2] = *(const uint4*)(wp + 16); pb[3] = *(const uint4*)(wp + 24);
    }

    f32x4 acc[2][4];
    #pragma unroll
    for (int i = 0; i < 2; ++i)
        #pragma unroll
        for (int n = 0; n < 4; ++n) acc[i][n] = f32x4{0.f, 0.f, 0.f, 0.f};

    for (int k0 = 0; k0 < DMODEL; k0 += 64) {
        __syncthreads();
        *(uint4*)&As[ar][ac]      = pa0;
        *(uint4*)&As[ar][ac + 8]  = pa1;
        *(uint4*)&Bs[br][bc]      = pb[0];
        *(uint4*)&Bs[br][bc + 8]  = pb[1];
        *(uint4*)&Bs[br][bc + 16] = pb[2];
        *(uint4*)&Bs[br][bc + 24] = pb[3];
        __syncthreads();
        {
            const int k0n = (k0 + 64 < DMODEL) ? k0 + 64 : k0;
            const unsigned short* ap = ctx + (size_t)(m0 + ar) * DMODEL + k0n + ac;
            pa0 = *(const uint4*)ap;
            pa1 = *(const uint4*)(ap + 8);
            const unsigned short* wp = Wt + (size_t)(n0 + br) * DMODEL + k0n + bc;
            pb[0] = *(const uint4*)wp;        pb[1] = *(const uint4*)(wp + 8);
            pb[2] = *(const uint4*)(wp + 16); pb[3] = *(const uint4*)(wp + 24);
        }
        #pragma unroll
        for (int s = 0; s < 2; ++s) {
            bf16x8 af[2];   // A-operand = Wt dims (wave-partitioned 32 rows)
            #pragma unroll
            for (int i = 0; i < 2; ++i)
                af[i] = *(const bf16x8*)&Bs[wave * 32 + i * 16 + lrow][s * 32 + quad * 8];
            #pragma unroll
            for (int n = 0; n < 4; ++n) {
                bf16x8 bf = *(const bf16x8*)&As[n * 16 + lrow][s * 32 + quad * 8];
                acc[0][n] = __builtin_amdgcn_mfma_f32_16x16x32_bf16(af[0], bf, acc[0][n], 0, 0, 0);
                acc[1][n] = __builtin_amdgcn_mfma_f32_16x16x32_bf16(af[1], bf, acc[1][n], 0, 0, 0);
            }
        }
    }

    // rows = dim (consecutive accs = consecutive dims) -> float4 stores
    #pragma unroll
    for (int i = 0; i < 2; ++i) {
        const int dimb = n0 + wave * 32 + i * 16 + quad * 4;
        const float4 b4 = *(const float4*)&bo[dimb];
        #pragma unroll
        for (int n = 0; n < 4; ++n) {
            const int tok = m0 + n * 16 + lrow;
            float4 o;
            o.x = acc[i][n][0] + b4.x;
            o.y = acc[i][n][1] + b4.y;
            o.z = acc[i][n][2] + b4.z;
            o.w = acc[i][n][3] + b4.w;
            *(float4*)&out[(size_t)tok * DMODEL + dimb] = o;
        }
    }
}

// ---------------------------------------------------------------------------
extern "C" void kernel_launch(void* const* d_in, const int* in_sizes, int n_in,
                              void* d_out, int out_size, void* d_ws, size_t ws_size,
                              hipStream_t stream)
{
    const float* qin = (const float*)d_in[0];
    const float* kin = (const float*)d_in[1];
    const float* vin = (const float*)d_in[2];
    const float* Wq  = (const float*)d_in[3];
    const float* bq  = (const float*)d_in[4];
    const float* Wk  = (const float*)d_in[5];
    const float* bk  = (const float*)d_in[6];
    const float* Wv  = (const float*)d_in[7];
    const float* bv  = (const float*)d_in[8];
    const float* Wo  = (const float*)d_in[9];
    const float* bo  = (const float*)d_in[10];

    unsigned short* ws = (unsigned short*)d_ws;
    float* out = (float*)d_out;

    dim3 gw(DMODEL / 32, DMODEL / 32, 4);
    wt_prep_kernel<<<gw, 256, 0, stream>>>(Wq, Wk, Wv, Wo, ws + WS_WT);

    dim3 gi(QSIZE / (256 * 8), 3);
    inp_prep_kernel<<<gi, 256, 0, stream>>>(qin, kin, vin, ws + WS_ABF);

    dim3 gp(DMODEL / 128, MTOT / 128, 3);
    qkv_mfma_kernel<<<gp, 256, 0, stream>>>(ws, bq, bk, bv);

    dim3 ga(BATCH * NH, SEQ / 128);
    attn_mfma_kernel<<<ga, 256, 0, stream>>>(ws, ws + WS_CTX);

    dim3 go(DMODEL / 128, MTOT / 64);
    out_proj_mfma_kernel<<<go, 256, 0, stream>>>(ws, bo, out);
}

// Round 7
// 211.630 us; speedup vs baseline: 1.1336x; 1.1336x over previous
//
#include <hip/hip_runtime.h>
#include <math.h>

#define BATCH 2
#define SEQ 2048
#define DMODEL 512
#define NH 8
#define HDIM 64
#define MTOT (BATCH * SEQ)              // 4096
#define QSIZE (BATCH * NH * SEQ * HDIM) // 2097152 elems per tensor
#define WSIZE (DMODEL * DMODEL)         // 262144 elems per weight

typedef __attribute__((ext_vector_type(8))) short bf16x8;
typedef __attribute__((ext_vector_type(16))) float f32x16;

__device__ inline unsigned short f2bf(float f) {
    union { float f; unsigned u; } v; v.f = f;
    unsigned u = v.u;
    u += 0x7fffu + ((u >> 16) & 1u);
    return (unsigned short)(u >> 16);
}
__device__ inline unsigned pack2(float lo, float hi) {
    return (unsigned)f2bf(lo) | ((unsigned)f2bf(hi) << 16);
}

// LDS row stride: 72 elems = 144 B. 16B-aligned (b128), 9 x 16B-groups per
// row -> 32-row x 2-half lane patterns hit each of the 8 bank-groups with
// exactly 8 lanes: balanced, conflict-free for 32x32 fragment reads.
#define LSTR 72

// ws layout (bf16 elems):
#define WS_Q   ((size_t)0)
#define WS_K   ((size_t)QSIZE)
#define WS_V   (2 * (size_t)QSIZE)        // [B,H,HD,S] transposed
#define WS_CTX (3 * (size_t)QSIZE)
#define WS_WT  (4 * (size_t)QSIZE)        // 4 transposed weights (bf16 [n][k])

// 32x32x16 bf16 MFMA layouts (verified m74/m101):
//   A[m][k]: m = lane&31, k = (lane>>5)*8 + j   (8 elems, b128)
//   B[k][n]: n = lane&31, k = (lane>>5)*8 + j
//   C/D:     col = lane&31, row = (reg&3) + 8*(reg>>2) + 4*(lane>>5)

// ---------------------------------------------------------------------------
// Kernel 0: transpose + bf16-convert the 4 weight matrices.
// ---------------------------------------------------------------------------
__global__ __launch_bounds__(256) void wt_prep_kernel(
    const float* __restrict__ Wq, const float* __restrict__ Wk,
    const float* __restrict__ Wv, const float* __restrict__ Wo,
    unsigned short* __restrict__ wt)
{
    const int z = blockIdx.z;
    const float* W = (z == 0) ? Wq : (z == 1) ? Wk : (z == 2) ? Wv : Wo;
    unsigned short* Wt = wt + (size_t)z * WSIZE;

    __shared__ float T[32][33];
    const int tid = threadIdx.x;
    const int k0 = blockIdx.x * 32, n0 = blockIdx.y * 32;

    {
        int r = tid >> 3, c = (tid & 7) * 4;
        float4 v = *(const float4*)&W[(size_t)(k0 + r) * DMODEL + n0 + c];
        T[r][c + 0] = v.x; T[r][c + 1] = v.y; T[r][c + 2] = v.z; T[r][c + 3] = v.w;
    }
    __syncthreads();
    {
        int n = tid >> 3, c = (tid & 7) * 4;
        uint2 o;
        o.x = pack2(T[c + 0][n], T[c + 1][n]);
        o.y = pack2(T[c + 2][n], T[c + 3][n]);
        *(uint2*)&Wt[(size_t)(n0 + n) * DMODEL + k0 + c] = o;
    }
}

// ---------------------------------------------------------------------------
// Kernel 1a: Q/K projection, 32x32 MFMA, A-operand = Wt (C rows = head-dim).
// Tile 128 tokens x 128 dims; wave owns 64 dims x 64 tokens (2x2 32-tiles).
// fp32 input converted to bf16 during staging. Q scaled 0.125.
// grid (4, 32, 2): x = dim-block, y = token-block, z = {Q, K}.
// ---------------------------------------------------------------------------
__global__ __launch_bounds__(256) void qkv_qk_kernel(
    const float* __restrict__ qin, const float* __restrict__ kin,
    const float* __restrict__ bq, const float* __restrict__ bk,
    unsigned short* __restrict__ ws)
{
    const int which = blockIdx.z;
    const float* A    = (which == 0) ? qin : kin;
    const float* bias = (which == 0) ? bq : bk;
    const unsigned short* Wt = ws + WS_WT + (size_t)which * WSIZE;
    unsigned short* out = ws + (size_t)which * QSIZE;

    __shared__ __align__(16) short As[128][LSTR];  // tokens x k
    __shared__ __align__(16) short Bs[128][LSTR];  // dims x k

    const int tid = threadIdx.x;
    const int lane = tid & 63, w = tid >> 6;
    const int ql = lane & 31, h = lane >> 5;
    const int m0 = blockIdx.y * 128, n0 = blockIdx.x * 128;

    const int sr = tid >> 1, sh = (tid & 1) * 32;   // staging row / col-half

    f32x16 acc[2][2];   // [i: dim 32-tile][j: token 32-tile]
    #pragma unroll
    for (int i = 0; i < 2; ++i)
        #pragma unroll
        for (int j = 0; j < 2; ++j)
            #pragma unroll
            for (int r = 0; r < 16; ++r) acc[i][j][r] = 0.f;

    const int dw = (w >> 1) * 64;   // wave dim-block
    const int tw = (w & 1) * 64;    // wave token-block

    for (int k0 = 0; k0 < DMODEL; k0 += 64) {
        __syncthreads();
        {   // stage A (fp32 -> bf16)
            const float* ap = A + (size_t)(m0 + sr) * DMODEL + k0 + sh;
            float4 a0 = *(const float4*)(ap + 0),  a1 = *(const float4*)(ap + 4);
            float4 a2 = *(const float4*)(ap + 8),  a3 = *(const float4*)(ap + 12);
            float4 a4 = *(const float4*)(ap + 16), a5 = *(const float4*)(ap + 20);
            float4 a6 = *(const float4*)(ap + 24), a7 = *(const float4*)(ap + 28);
            uint4 h0 = {pack2(a0.x,a0.y), pack2(a0.z,a0.w), pack2(a1.x,a1.y), pack2(a1.z,a1.w)};
            uint4 h1 = {pack2(a2.x,a2.y), pack2(a2.z,a2.w), pack2(a3.x,a3.y), pack2(a3.z,a3.w)};
            uint4 h2 = {pack2(a4.x,a4.y), pack2(a4.z,a4.w), pack2(a5.x,a5.y), pack2(a5.z,a5.w)};
            uint4 h3 = {pack2(a6.x,a6.y), pack2(a6.z,a6.w), pack2(a7.x,a7.y), pack2(a7.z,a7.w)};
            *(uint4*)&As[sr][sh + 0]  = h0;
            *(uint4*)&As[sr][sh + 8]  = h1;
            *(uint4*)&As[sr][sh + 16] = h2;
            *(uint4*)&As[sr][sh + 24] = h3;
        }
        {   // stage B (bf16 copy from Wt[n][k])
            const unsigned short* wp = Wt + (size_t)(n0 + sr) * DMODEL + k0 + sh;
            uint4 b0 = *(const uint4*)wp,        b1 = *(const uint4*)(wp + 8);
            uint4 b2 = *(const uint4*)(wp + 16), b3 = *(const uint4*)(wp + 24);
            *(uint4*)&Bs[sr][sh + 0]  = b0;
            *(uint4*)&Bs[sr][sh + 8]  = b1;
            *(uint4*)&Bs[sr][sh + 16] = b2;
            *(uint4*)&Bs[sr][sh + 24] = b3;
        }
        __syncthreads();
        #pragma unroll
        for (int s = 0; s < 4; ++s) {   // 4 k-steps of 16
            bf16x8 a[2], b[2];
            #pragma unroll
            for (int i = 0; i < 2; ++i)
                a[i] = *(const bf16x8*)&Bs[dw + i * 32 + ql][s * 16 + h * 8];
            #pragma unroll
            for (int j = 0; j < 2; ++j)
                b[j] = *(const bf16x8*)&As[tw + j * 32 + ql][s * 16 + h * 8];
            #pragma unroll
            for (int i = 0; i < 2; ++i)
                #pragma unroll
                for (int j = 0; j < 2; ++j)
                    acc[i][j] = __builtin_amdgcn_mfma_f32_32x32x16_bf16(a[i], b[j], acc[i][j], 0, 0, 0);
        }
    }

    // epilogue: rows = dim, cols = token; [B,H,S,HD] uint2 over hd.
    const float scale = (which == 0) ? 0.125f : 1.0f;
    #pragma unroll
    for (int i = 0; i < 2; ++i) {
        #pragma unroll
        for (int g = 0; g < 4; ++g) {
            const int dim = n0 + dw + i * 32 + 8 * g + 4 * h;
            const float4 b4 = *(const float4*)&bias[dim];
            const int h_ = dim >> 6, hd_ = dim & 63;
            #pragma unroll
            for (int j = 0; j < 2; ++j) {
                const int tok = m0 + tw + j * 32 + ql;
                const int b_ = tok >> 11, s_ = tok & (SEQ - 1);
                uint2 o;
                o.x = pack2((acc[i][j][4 * g + 0] + b4.x) * scale,
                            (acc[i][j][4 * g + 1] + b4.y) * scale);
                o.y = pack2((acc[i][j][4 * g + 2] + b4.z) * scale,
                            (acc[i][j][4 * g + 3] + b4.w) * scale);
                *(uint2*)&out[((size_t)((b_ * NH + h_) * SEQ + s_)) * HDIM + hd_] = o;
            }
        }
    }
}

// ---------------------------------------------------------------------------
// Kernel 1b: V projection, 32x32 MFMA, A-operand = tokens (C rows = token).
// Output [B,H,HD,S] with uint2 stores over s. grid (4, 32).
// ---------------------------------------------------------------------------
__global__ __launch_bounds__(256) void qkv_v_kernel(
    const float* __restrict__ vin, const float* __restrict__ bv,
    unsigned short* __restrict__ ws)
{
    const float* A = vin;
    const unsigned short* Wt = ws + WS_WT + 2 * (size_t)WSIZE;
    unsigned short* out = ws + WS_V;

    __shared__ __align__(16) short As[128][LSTR];
    __shared__ __align__(16) short Bs[128][LSTR];

    const int tid = threadIdx.x;
    const int lane = tid & 63, w = tid >> 6;
    const int ql = lane & 31, h = lane >> 5;
    const int m0 = blockIdx.y * 128, n0 = blockIdx.x * 128;

    const int sr = tid >> 1, sh = (tid & 1) * 32;

    f32x16 acc[2][2];   // [i: token 32-tile][j: dim 32-tile]
    #pragma unroll
    for (int i = 0; i < 2; ++i)
        #pragma unroll
        for (int j = 0; j < 2; ++j)
            #pragma unroll
            for (int r = 0; r < 16; ++r) acc[i][j][r] = 0.f;

    const int tw = (w >> 1) * 64;   // wave token-block
    const int dw = (w & 1) * 64;    // wave dim-block

    for (int k0 = 0; k0 < DMODEL; k0 += 64) {
        __syncthreads();
        {
            const float* ap = A + (size_t)(m0 + sr) * DMODEL + k0 + sh;
            float4 a0 = *(const float4*)(ap + 0),  a1 = *(const float4*)(ap + 4);
            float4 a2 = *(const float4*)(ap + 8),  a3 = *(const float4*)(ap + 12);
            float4 a4 = *(const float4*)(ap + 16), a5 = *(const float4*)(ap + 20);
            float4 a6 = *(const float4*)(ap + 24), a7 = *(const float4*)(ap + 28);
            uint4 h0 = {pack2(a0.x,a0.y), pack2(a0.z,a0.w), pack2(a1.x,a1.y), pack2(a1.z,a1.w)};
            uint4 h1 = {pack2(a2.x,a2.y), pack2(a2.z,a2.w), pack2(a3.x,a3.y), pack2(a3.z,a3.w)};
            uint4 h2 = {pack2(a4.x,a4.y), pack2(a4.z,a4.w), pack2(a5.x,a5.y), pack2(a5.z,a5.w)};
            uint4 h3 = {pack2(a6.x,a6.y), pack2(a6.z,a6.w), pack2(a7.x,a7.y), pack2(a7.z,a7.w)};
            *(uint4*)&As[sr][sh + 0]  = h0;
            *(uint4*)&As[sr][sh + 8]  = h1;
            *(uint4*)&As[sr][sh + 16] = h2;
            *(uint4*)&As[sr][sh + 24] = h3;
        }
        {
            const unsigned short* wp = Wt + (size_t)(n0 + sr) * DMODEL + k0 + sh;
            uint4 b0 = *(const uint4*)wp,        b1 = *(const uint4*)(wp + 8);
            uint4 b2 = *(const uint4*)(wp + 16), b3 = *(const uint4*)(wp + 24);
            *(uint4*)&Bs[sr][sh + 0]  = b0;
            *(uint4*)&Bs[sr][sh + 8]  = b1;
            *(uint4*)&Bs[sr][sh + 16] = b2;
            *(uint4*)&Bs[sr][sh + 24] = b3;
        }
        __syncthreads();
        #pragma unroll
        for (int s = 0; s < 4; ++s) {
            bf16x8 a[2], b[2];
            #pragma unroll
            for (int i = 0; i < 2; ++i)
                a[i] = *(const bf16x8*)&As[tw + i * 32 + ql][s * 16 + h * 8];
            #pragma unroll
            for (int j = 0; j < 2; ++j)
                b[j] = *(const bf16x8*)&Bs[dw + j * 32 + ql][s * 16 + h * 8];
            #pragma unroll
            for (int i = 0; i < 2; ++i)
                #pragma unroll
                for (int j = 0; j < 2; ++j)
                    acc[i][j] = __builtin_amdgcn_mfma_f32_32x32x16_bf16(a[i], b[j], acc[i][j], 0, 0, 0);
        }
    }

    // epilogue: rows = token (runs of 4 consecutive s), cols = dim.
    #pragma unroll
    for (int j = 0; j < 2; ++j) {
        const int dim = n0 + dw + j * 32 + ql;
        const int h_ = dim >> 6, hd_ = dim & 63;
        const float bv_ = bv[dim];
        #pragma unroll
        for (int i = 0; i < 2; ++i) {
            #pragma unroll
            for (int g = 0; g < 4; ++g) {
                const int tok = m0 + tw + i * 32 + 8 * g + 4 * h;
                const int b_ = tok >> 11, s_ = tok & (SEQ - 1);
                uint2 o;
                o.x = pack2(acc[i][j][4 * g + 0] + bv_, acc[i][j][4 * g + 1] + bv_);
                o.y = pack2(acc[i][j][4 * g + 2] + bv_, acc[i][j][4 * g + 3] + bv_);
                *(uint2*)&out[((size_t)((b_ * NH + h_) * HDIM + hd_)) * SEQ + s_] = o;
            }
        }
    }
}

// ---------------------------------------------------------------------------
// Kernel 2: flash attention, 32x32 MFMA, S^T formulation.
// grid (B*H = 16, S/128 = 16), 256 thr; wave owns 32 q (one q per lane-pair).
// S^T = K.Q^T: C col = q, rows = key -> lane holds 32 of its q's 64 scores;
// partner lane^32 holds the rest. O^T = V^T.P^T accumulated in C-layout.
// ---------------------------------------------------------------------------
__global__ __launch_bounds__(256) void attn_mfma_kernel(
    const unsigned short* __restrict__ ws, unsigned short* __restrict__ ctx)
{
    const unsigned short* Q = ws + WS_Q;   // pre-scaled by 0.125
    const unsigned short* K = ws + WS_K;
    const unsigned short* V = ws + WS_V;   // [B,H,HD,S]

    __shared__ __align__(16) short Ks[64][LSTR];   // K[key][hd]
    __shared__ __align__(16) short Vt[64][LSTR];   // V^T[hd][key]
    __shared__ __align__(16) short Ps[128][LSTR];  // P[q][key] (wave-private rows)

    const int bh = blockIdx.x;
    const int q0 = blockIdx.y * 128;
    const int tid = threadIdx.x;
    const int lane = tid & 63, w = tid >> 6;
    const int ql = lane & 31, h = lane >> 5;
    const size_t base = (size_t)bh * SEQ * HDIM;
    const int q = q0 + w * 32 + ql;

    // Q B-operand frags: qf[s] = Q[q][s*16 + h*8 .. +7]
    bf16x8 qf[4];
    {
        const unsigned short* qr = Q + base + (size_t)q * HDIM;
        #pragma unroll
        for (int s = 0; s < 4; ++s) qf[s] = *(const bf16x8*)(qr + s * 16 + h * 8);
    }

    float m_prev = -1e30f, l_run = 0.f;
    f32x16 oacc[2];   // O^T d-tiles; col = q, row = d
    #pragma unroll
    for (int dt = 0; dt < 2; ++dt)
        #pragma unroll
        for (int r = 0; r < 16; ++r) oacc[dt][r] = 0.f;

    const int kr = tid >> 2, kc = (tid & 3) * 16;  // staging: row, 16-col quarter

    uint4 kpre[2], vpre[2];
    {
        const unsigned short* kp = K + base + (size_t)kr * HDIM + kc;
        kpre[0] = *(const uint4*)kp;  kpre[1] = *(const uint4*)(kp + 8);
        const unsigned short* vp = V + base + (size_t)kr * SEQ + kc;
        vpre[0] = *(const uint4*)vp;  vpre[1] = *(const uint4*)(vp + 8);
    }

    for (int kt = 0; kt < SEQ; kt += 64) {
        __syncthreads();
        *(uint4*)&Ks[kr][kc]     = kpre[0];
        *(uint4*)&Ks[kr][kc + 8] = kpre[1];
        *(uint4*)&Vt[kr][kc]     = vpre[0];
        *(uint4*)&Vt[kr][kc + 8] = vpre[1];
        __syncthreads();
        {   // prefetch next tile (clamped; redundant reload on last iter)
            const int ktn = (kt + 64 < SEQ) ? kt + 64 : kt;
            const unsigned short* kp = K + base + (size_t)(ktn + kr) * HDIM + kc;
            kpre[0] = *(const uint4*)kp;  kpre[1] = *(const uint4*)(kp + 8);
            const unsigned short* vp = V + base + (size_t)kr * SEQ + ktn + kc;
            vpre[0] = *(const uint4*)vp;  vpre[1] = *(const uint4*)(vp + 8);
        }

        // ---- S^T = K.Q^T : st[m], keys m*32 + (reg&3)+8*(reg>>2)+4h ----
        f32x16 st[2];
        #pragma unroll
        for (int m = 0; m < 2; ++m) {
            f32x16 z;
            #pragma unroll
            for (int r = 0; r < 16; ++r) z[r] = 0.f;
            #pragma unroll
            for (int s = 0; s < 4; ++s) {
                bf16x8 ka = *(const bf16x8*)&Ks[m * 32 + ql][s * 16 + h * 8];
                z = __builtin_amdgcn_mfma_f32_32x32x16_bf16(ka, qf[s], z, 0, 0, 0);
            }
            st[m] = z;
        }

        // ---- online softmax for q: 32 in-lane scores + partner lane^32 ----
        float tmax = st[0][0];
        #pragma unroll
        for (int m = 0; m < 2; ++m)
            #pragma unroll
            for (int r = 0; r < 16; ++r) tmax = fmaxf(tmax, st[m][r]);
        tmax = fmaxf(tmax, __shfl_xor(tmax, 32));

        const float mnew = fmaxf(m_prev, tmax);
        const float alpha = __expf(m_prev - mnew);
        float tsum = 0.f;
        #pragma unroll
        for (int m = 0; m < 2; ++m)
            #pragma unroll
            for (int r = 0; r < 16; ++r) {
                st[m][r] = __expf(st[m][r] - mnew);
                tsum += st[m][r];
            }
        tsum += __shfl_xor(tsum, 32);
        l_run = l_run * alpha + tsum;
        m_prev = mnew;
        #pragma unroll
        for (int dt = 0; dt < 2; ++dt)
            #pragma unroll
            for (int r = 0; r < 16; ++r) oacc[dt][r] *= alpha;

        // ---- write P[q][key]: key = m*32 + 8g + 4h + r ----
        const int prow = w * 32 + ql;
        #pragma unroll
        for (int m = 0; m < 2; ++m)
            #pragma unroll
            for (int g = 0; g < 4; ++g) {
                uint2 o;
                o.x = pack2(st[m][4 * g + 0], st[m][4 * g + 1]);
                o.y = pack2(st[m][4 * g + 2], st[m][4 * g + 3]);
                *(uint2*)&Ps[prow][m * 32 + 8 * g + 4 * h] = o;
            }
        // Ps rows wave-private: lgkmcnt ordering suffices, no barrier.

        // ---- O^T += V^T.P^T ----
        #pragma unroll
        for (int s = 0; s < 4; ++s) {
            bf16x8 pf = *(const bf16x8*)&Ps[prow][s * 16 + h * 8];
            #pragma unroll
            for (int dt = 0; dt < 2; ++dt) {
                bf16x8 va = *(const bf16x8*)&Vt[dt * 32 + ql][s * 16 + h * 8];
                oacc[dt] = __builtin_amdgcn_mfma_f32_32x32x16_bf16(va, pf, oacc[dt], 0, 0, 0);
            }
        }
    }

    // ---- epilogue: normalize, ctx [B,S,D] bf16, d runs of 4 -> uint2 ----
    const int b_ = bh >> 3, h_ = bh & 7;
    const float inv = 1.f / l_run;
    unsigned short* crow = ctx + ((size_t)(b_ * SEQ + q)) * DMODEL + h_ * HDIM;
    #pragma unroll
    for (int dt = 0; dt < 2; ++dt)
        #pragma unroll
        for (int g = 0; g < 4; ++g) {
            uint2 o;
            o.x = pack2(oacc[dt][4 * g + 0] * inv, oacc[dt][4 * g + 1] * inv);
            o.y = pack2(oacc[dt][4 * g + 2] * inv, oacc[dt][4 * g + 3] * inv);
            *(uint2*)&crow[dt * 32 + 8 * g + 4 * h] = o;
        }
}

// ---------------------------------------------------------------------------
// Kernel 3: output projection, 32x32 MFMA, A-operand = Wt (C rows = dim).
// Tile 64 tokens x 128 dims; wave owns 32 dims x 64 tokens. grid (4, 64).
// fp32 epilogue with float4 stores.
// ---------------------------------------------------------------------------
__global__ __launch_bounds__(256) void out_proj_mfma_kernel(
    const unsigned short* __restrict__ ws, const float* __restrict__ bo,
    float* __restrict__ out)
{
    const unsigned short* ctx = ws + WS_CTX;
    const unsigned short* Wt  = ws + WS_WT + 3 * (size_t)WSIZE;

    __shared__ __align__(16) short As[64][LSTR];   // tokens x k
    __shared__ __align__(16) short Bs[128][LSTR];  // dims x k

    const int tid = threadIdx.x;
    const int lane = tid & 63, w = tid >> 6;
    const int ql = lane & 31, h = lane >> 5;
    const int m0 = blockIdx.y * 64, n0 = blockIdx.x * 128;

    const int ar = tid >> 2, ac = (tid & 3) * 16;   // As: row, 16-col quarter
    const int br = tid >> 1, bc = (tid & 1) * 32;   // Bs: row, 32-col half

    f32x16 acc[2];   // [j: token 32-tile]; rows = dim (w*32 block)
    #pragma unroll
    for (int j = 0; j < 2; ++j)
        #pragma unroll
        for (int r = 0; r < 16; ++r) acc[j][r] = 0.f;

    for (int k0 = 0; k0 < DMODEL; k0 += 64) {
        __syncthreads();
        {
            const unsigned short* ap = ctx + (size_t)(m0 + ar) * DMODEL + k0 + ac;
            uint4 c0 = *(const uint4*)ap, c1 = *(const uint4*)(ap + 8);
            *(uint4*)&As[ar][ac]     = c0;
            *(uint4*)&As[ar][ac + 8] = c1;
        }
        {
            const unsigned short* wp = Wt + (size_t)(n0 + br) * DMODEL + k0 + bc;
            uint4 b0 = *(const uint4*)wp,        b1 = *(const uint4*)(wp + 8);
            uint4 b2 = *(const uint4*)(wp + 16), b3 = *(const uint4*)(wp + 24);
            *(uint4*)&Bs[br][bc]      = b0;
            *(uint4*)&Bs[br][bc + 8]  = b1;
            *(uint4*)&Bs[br][bc + 16] = b2;
            *(uint4*)&Bs[br][bc + 24] = b3;
        }
        __syncthreads();
        #pragma unroll
        for (int s = 0; s < 4; ++s) {
            bf16x8 a = *(const bf16x8*)&Bs[w * 32 + ql][s * 16 + h * 8];
            #pragma unroll
            for (int j = 0; j < 2; ++j) {
                bf16x8 b = *(const bf16x8*)&As[j * 32 + ql][s * 16 + h * 8];
                acc[j] = __builtin_amdgcn_mfma_f32_32x32x16_bf16(a, b, acc[j], 0, 0, 0);
            }
        }
    }

    // epilogue: dim runs of 4 -> float4 stores.
    #pragma unroll
    for (int g = 0; g < 4; ++g) {
        const int dim = n0 + w * 32 + 8 * g + 4 * h;
        const float4 b4 = *(const float4*)&bo[dim];
        #pragma unroll
        for (int j = 0; j < 2; ++j) {
            const int tok = m0 + j * 32 + ql;
            float4 o;
            o.x = acc[j][4 * g + 0] + b4.x;
            o.y = acc[j][4 * g + 1] + b4.y;
            o.z = acc[j][4 * g + 2] + b4.z;
            o.w = acc[j][4 * g + 3] + b4.w;
            *(float4*)&out[(size_t)tok * DMODEL + dim] = o;
        }
    }
}

// ---------------------------------------------------------------------------
extern "C" void kernel_launch(void* const* d_in, const int* in_sizes, int n_in,
                              void* d_out, int out_size, void* d_ws, size_t ws_size,
                              hipStream_t stream)
{
    const float* qin = (const float*)d_in[0];
    const float* kin = (const float*)d_in[1];
    const float* vin = (const float*)d_in[2];
    const float* Wq  = (const float*)d_in[3];
    const float* bq  = (const float*)d_in[4];
    const float* Wk  = (const float*)d_in[5];
    const float* bk  = (const float*)d_in[6];
    const float* Wv  = (const float*)d_in[7];
    const float* bv  = (const float*)d_in[8];
    const float* Wo  = (const float*)d_in[9];
    const float* bo  = (const float*)d_in[10];

    unsigned short* ws = (unsigned short*)d_ws;
    float* out = (float*)d_out;

    dim3 gw(DMODEL / 32, DMODEL / 32, 4);
    wt_prep_kernel<<<gw, 256, 0, stream>>>(Wq, Wk, Wv, Wo, ws + WS_WT);

    dim3 gqk(DMODEL / 128, MTOT / 128, 2);
    qkv_qk_kernel<<<gqk, 256, 0, stream>>>(qin, kin, bq, bk, ws);

    dim3 gv(DMODEL / 128, MTOT / 128);
    qkv_v_kernel<<<gv, 256, 0, stream>>>(vin, bv, ws);

    dim3 ga(BATCH * NH, SEQ / 128);
    attn_mfma_kernel<<<ga, 256, 0, stream>>>(ws, ws + WS_CTX);

    dim3 go(DMODEL / 128, MTOT / 64);
    out_proj_mfma_kernel<<<go, 256, 0, stream>>>(ws, bo, out);
}